// Round 7
// baseline (378.057 us; speedup 1.0000x reference)
//
#include <hip/hip_runtime.h>
#include <math.h>

#define T_TOKENS 32768
#define HIDDEN   2048
#define NE       8
#define BLOCK    512                    // 8 waves = 8 chunks of 256 floats
#define GRID     (T_TOKENS / 64)        // 512 teams, 64 tokens each
#define NGRP     32                     // groups of 2 tokens per team
#define DPD      4                      // prefetch depth in groups

// ws layout (floats): [0..7]=importance sums, [8..15]=load counts, [16]=sum(lse^2)
__global__ __launch_bounds__(BLOCK, 2) void router_main(
    const float* __restrict__ x, const float* __restrict__ W,
    float* __restrict__ out, float* __restrict__ ws)
{
    __shared__ float red[2][8][16];     // [parity][wave][token*8+expert]
    __shared__ float s_acc[17];
    if (threadIdx.x < 17) s_acc[threadIdx.x] = 0.0f;

    const int lane  = threadIdx.x & 63;
    const int wid   = threadIdx.x >> 6;          // chunk this wave owns, 0..7
    const int tbase = blockIdx.x * 64;           // first token of this team

    // Loop-invariant W fragment: 8 experts x 4 floats per lane (32 VGPRs).
    float4 wv[NE];
    {
        const float* wb = W + wid * 256 + lane * 4;
#pragma unroll
        for (int e = 0; e < NE; ++e)
            wv[e] = *(const float4*)(wb + e * HIDDEN);
    }

    // Per-lane global base for this wave's chunk slice.
    const float* xb = x + (size_t)tbase * HIDDEN + wid * 256 + lane * 4;
#define XLOAD(g, t) (*(const float4*)(xb + (size_t)(2 * (g) + (t)) * HIDDEN))

    // 4-group rolling prefetch in named registers (all indices static).
    float4 b0a = XLOAD(0, 0), b0b = XLOAD(0, 1);
    float4 b1a = XLOAD(1, 0), b1b = XLOAD(1, 1);
    float4 b2a = XLOAD(2, 0), b2b = XLOAD(2, 1);
    float4 b3a = XLOAD(3, 0), b3b = XLOAD(3, 1);

#define STEP(K, BA, BB)                                                         \
    do {                                                                        \
        const int g  = 4 * j + (K);                                             \
        const int t0 = tbase + 2 * g;                                           \
        float v[16];                                                            \
        _Pragma("unroll")                                                       \
        for (int e = 0; e < NE; ++e) {                                          \
            v[e]      = fmaf(BA.x, wv[e].x, fmaf(BA.y, wv[e].y,                 \
                        fmaf(BA.z, wv[e].z, BA.w * wv[e].w)));                  \
            v[NE + e] = fmaf(BB.x, wv[e].x, fmaf(BB.y, wv[e].y,                 \
                        fmaf(BB.z, wv[e].z, BB.w * wv[e].w)));                  \
        }                                                                       \
        if (j < NGRP / 4 - 1) {        /* refill this slot, 4 groups ahead */   \
            BA = XLOAD(g + DPD, 0);                                             \
            BB = XLOAD(g + DPD, 1);                                             \
        }                                                                       \
        /* value-pairing butterfly: 16 values -> lane l holds value (l&15) */   \
        _Pragma("unroll")                                                       \
        for (int st = 0; st < 4; ++st) {                                        \
            const int mm = 1 << st;                                             \
            const int nn = 16 >> st;                                            \
            const bool hi = (lane & mm) != 0;                                   \
            _Pragma("unroll")                                                   \
            for (int q = 0; q < nn / 2; ++q) {                                  \
                const float a = v[2 * q], b = v[2 * q + 1];                     \
                const float keep = hi ? b : a;                                  \
                const float send = hi ? a : b;                                  \
                v[q] = keep + __shfl_xor(send, mm, 64);                         \
            }                                                                   \
        }                                                                       \
        v[0] += __shfl_xor(v[0], 16, 64);                                       \
        v[0] += __shfl_xor(v[0], 32, 64);                                       \
        if (lane < 16) red[(K) & 1][wid][lane] = v[0];                          \
        __syncthreads();                                                        \
        if (wid == (g & 7)) {          /* rotating epilogue wave */             \
            const int e  = lane & 7;                                            \
            const int tk = t0 + ((lane >> 3) & 1);                              \
            float lg = 0.0f;                                                    \
            _Pragma("unroll")                                                   \
            for (int w = 0; w < 8; ++w) lg += red[(K) & 1][w][lane & 15];       \
            float mx = lg;                                                      \
            _Pragma("unroll")                                                   \
            for (int m2 = 1; m2 <= 4; m2 <<= 1)                                 \
                mx = fmaxf(mx, __shfl_xor(mx, m2, 64));                         \
            const float p = __expf(lg - mx);                                    \
            float sm = p;                                                       \
            _Pragma("unroll")                                                   \
            for (int m2 = 1; m2 <= 4; m2 <<= 1) sm += __shfl_xor(sm, m2, 64);   \
            const float inv  = 1.0f / sm;                                       \
            const float lse  = mx + __logf(sm);                                 \
            const float prob = p * inv;                                         \
            float bv = prob; int be = e;                                        \
            _Pragma("unroll")                                                   \
            for (int m2 = 1; m2 <= 4; m2 <<= 1) {                               \
                const float ov = __shfl_xor(bv, m2, 64);                        \
                const int   oe = __shfl_xor(be, m2, 64);                        \
                if (ov > bv || (ov == bv && oe < be)) { bv = ov; be = oe; }     \
            }                                                                   \
            float cv = (e == be) ? -1.0f : prob; int ce = e;                    \
            _Pragma("unroll")                                                   \
            for (int m2 = 1; m2 <= 4; m2 <<= 1) {                               \
                const float ov = __shfl_xor(cv, m2, 64);                        \
                const int   oe = __shfl_xor(ce, m2, 64);                        \
                if (ov > cv || (ov == cv && oe < ce)) { cv = ov; ce = oe; }     \
            }                                                                   \
            if (lane < 16) {                                                    \
                atomicAdd(&s_acc[e], prob);                                     \
                if (e == 0) {                                                   \
                    const float denom = fmaxf(bv + cv, 1e-9f);                  \
                    float2 ex = make_float2((float)be, (float)ce);              \
                    float2 sc = make_float2(bv / denom, cv / denom);            \
                    *(float2*)&out[2 * tk] = ex;                                \
                    *(float2*)&out[2 * T_TOKENS + 2 * tk] = sc;                 \
                    atomicAdd(&s_acc[8 + be], 1.0f);                            \
                    atomicAdd(&s_acc[16], lse * lse);                           \
                }                                                               \
            }                                                                   \
        }                                                                       \
    } while (0)

    for (int j = 0; j < NGRP / 4; ++j) {
        STEP(0, b0a, b0b);
        STEP(1, b1a, b1b);
        STEP(2, b2a, b2b);
        STEP(3, b3a, b3b);
    }

    __syncthreads();
    if (threadIdx.x < 17) atomicAdd(&ws[threadIdx.x], s_acc[threadIdx.x]);
}

__global__ void router_finalize(const float* __restrict__ ws, float* __restrict__ out)
{
    float impsum = 0.0f, loadsum = 0.0f;
#pragma unroll
    for (int e = 0; e < NE; ++e) { impsum += ws[e]; loadsum += ws[8 + e]; }
    impsum  = fmaxf(impsum, 1e-9f);
    loadsum = fmaxf(loadsum, 1e-9f);
    float lb = 0.0f;
#pragma unroll
    for (int e = 0; e < NE; ++e)
        lb += (ws[e] / impsum) * (ws[8 + e] / loadsum);
    lb *= (float)(NE * NE) * 0.01f;                    // * NUM_EXPERTS^2 * LB_LOSS_COEF
    const float z = ws[16] / (float)T_TOKENS * 0.001f; // mean(lse^2) * Z_LOSS_COEF

    out[4 * T_TOKENS + 0] = z;   // index 131072
    out[4 * T_TOKENS + 1] = lb;  // index 131073
}

extern "C" void kernel_launch(void* const* d_in, const int* in_sizes, int n_in,
                              void* d_out, int out_size, void* d_ws, size_t ws_size,
                              hipStream_t stream)
{
    const float* x = (const float*)d_in[0];
    const float* W = (const float*)d_in[1];
    float* out = (float*)d_out;
    float* ws  = (float*)d_ws;

    hipMemsetAsync(ws, 0, 17 * sizeof(float), stream);
    router_main<<<GRID, BLOCK, 0, stream>>>(x, W, out, ws);
    router_finalize<<<1, 1, 0, stream>>>(ws, out);
}